// Round 8
// baseline (351.256 us; speedup 1.0000x reference)
//
#include <hip/hip_runtime.h>
#include <cfloat>

typedef short  bf16x8 __attribute__((ext_vector_type(8)));
typedef float  f32x4  __attribute__((ext_vector_type(4)));
typedef unsigned int  uint;
typedef unsigned short ushort;

// Problem constants
constexpr int DIM  = 512;
constexpr int NEMB = 1024;
constexpr int HW   = 1024;
constexpr int NROW = 32 * HW;   // 32768

constexpr long long QCOUNT = (long long)32 * 512 * 32 * 32; // 16777216
constexpr long long SOFF   = QCOUNT;
constexpr long long IOFF   = SOFF + 1;

// ---------------- ws layout (bytes) ----------------
// zt: 256 mb x 16 kc tiles of (128r x 32k bf16, swizzled rows) = 8KB -> 32 MB each
// et: 4 nc x 16 kc tiles of 16KB, FRAGMENT-MAJOR: frag f (16 cols) x 1KB,
//     within frag: lane l (= hg*16+lr) at l*16  -> perfectly coalesced reg loads
constexpr size_t WS_ZHI   = 0;
constexpr size_t WS_ZLO   = 33554432;
constexpr size_t WS_EHI   = 67108864;
constexpr size_t WS_ELO   = 68157440;
constexpr size_t WS_ENORM = 69206016;
constexpr size_t WS_CNT   = 69210112;
constexpr size_t WS_LIST  = 69210368;
constexpr size_t WS_NEED  = WS_LIST + (size_t)NROW * 4;

constexpr float DELTA = 0.125f;  // recheck margin (>>100x bf16-split error bound)

// ---------------- helpers ----------------
__device__ __forceinline__ ushort bf16_rne(float x) {
    union { float f; uint u; } a; a.f = x;
    uint t = a.u + 0x7FFFu + ((a.u >> 16) & 1u);
    return (ushort)(t >> 16);
}
__device__ __forceinline__ float bf16_to_f(ushort h) {
    union { float f; uint u; } a; a.u = ((uint)h) << 16;
    return a.f;
}
__device__ __forceinline__ void gld16(const void* g, void* l) {
    __builtin_amdgcn_global_load_lds(
        (const __attribute__((address_space(1))) void*)g,
        (__attribute__((address_space(3))) void*)l, 16, 0, 0);
}
union PK8 { bf16x8 v; ushort u[8]; };

// A-tile granule swizzle (row = 64B = 4 x 16B granules): proven ~0 conflicts (r7)
__device__ __forceinline__ int swz_slot(int r, int g) {
    return g ^ ((r >> 1) & 3);
}

// ---------------- P1: embedding norms + counter zero ----------------
__global__ __launch_bounds__(256) void enorm_prep(const float* __restrict__ e,
                                                  float* __restrict__ enorm,
                                                  int* __restrict__ cnt) {
    if (blockIdx.x == 0 && threadIdx.x == 0) *cnt = 0;
    int gid  = blockIdx.x * 256 + threadIdx.x;
    int wave = gid >> 6;
    int lane = gid & 63;
    if (wave >= NEMB) return;
    const float* row = e + (size_t)wave * DIM;
    float4 a = *reinterpret_cast<const float4*>(row + lane * 8);
    float4 b = *reinterpret_cast<const float4*>(row + lane * 8 + 4);
    float s = a.x*a.x + a.y*a.y + a.z*a.z + a.w*a.w
            + b.x*b.x + b.y*b.y + b.z*b.z + b.w*b.w;
    #pragma unroll
    for (int off = 32; off > 0; off >>= 1) s += __shfl_down(s, off, 64);
    if (lane == 0) enorm[wave] = s;
}

// ---------------- P2: e -> et_hi / et_lo fragment-major tiles --------------
__global__ __launch_bounds__(256) void eprep(const float* __restrict__ e,
                                             char* __restrict__ et_hi,
                                             char* __restrict__ et_lo) {
    int gid = blockIdx.x * 256 + threadIdx.x;  // 0..65535
    int ke  = gid >> 6;                        // embedding row (col of B)
    int kbg = gid & 63;                        // 16B-granule (8 channels)
    const float* src = e + (size_t)ke * DIM + kbg * 8;
    PK8 h, lo;
    #pragma unroll
    for (int j = 0; j < 8; ++j) {
        float v = src[j];
        ushort hh = bf16_rne(v);
        h.u[j]  = hh;
        lo.u[j] = bf16_rne(v - bf16_to_f(hh));
    }
    int nc = ke >> 8, cT = ke & 255, f = cT >> 4, lr = cT & 15;
    int kc = kbg >> 2, hg = kbg & 3;
    size_t byte = ((size_t)(nc * 16 + kc)) * 16384
                + (size_t)f * 1024 + (size_t)hg * 256 + (size_t)lr * 16;
    *reinterpret_cast<bf16x8*>(et_hi + byte) = h.v;
    *reinterpret_cast<bf16x8*>(et_lo + byte) = lo.v;
}

// ---------------- P3: z -> zt_hi / zt_lo swizzled 128x32 tiles (transpose) -
__global__ __launch_bounds__(256) void zprep(const float* __restrict__ z,
                                             char* __restrict__ zt_hi,
                                             char* __restrict__ zt_lo) {
    __shared__ float ls[64][129];
    const int bx  = blockIdx.x;
    const int mb  = bx >> 3, kcc = bx & 7;     // kcc: 64-channel group
    const int b   = mb >> 3;                   // rows mb*128 -> batch
    const int hw0 = (mb & 7) * 128;
    const int t = threadIdx.x;
    for (int i = t; i < 64 * 128; i += 256) {
        int c = i >> 7, hw = i & 127;
        ls[c][hw] = z[((size_t)(b * DIM + kcc * 64 + c)) * HW + hw0 + hw];
    }
    __syncthreads();
    for (int j = t; j < 1024; j += 256) {
        int r = j >> 3, kbl = j & 7;
        PK8 h, lo;
        #pragma unroll
        for (int jj = 0; jj < 8; ++jj) {
            float v = ls[kbl * 8 + jj][r];
            ushort hh = bf16_rne(v);
            h.u[jj]  = hh;
            lo.u[jj] = bf16_rne(v - bf16_to_f(hh));
        }
        int kc = kcc * 2 + (kbl >> 2), g = kbl & 3;
        size_t byte = ((size_t)(mb * 16 + kc)) * 8192 + (size_t)r * 64
                    + ((size_t)swz_slot(r, g) << 4);
        *reinterpret_cast<bf16x8*>(zt_hi + byte) = h.v;
        *reinterpret_cast<bf16x8*>(zt_lo + byte) = lo.v;
    }
}

// ---------------- Main: 128x256 tile, A via LDS-dbuf, B direct-to-reg ------
// step body macro: static buffer roles (rule #20: no runtime-indexed reg arrays)
#define VQ_STEP(S, CUR, BCH, BCL, BNH, BNL)                                    \
  {                                                                            \
    if ((S) + 1 < 64) {                                                        \
      const int nn = ((S) + 1) >> 4, nk = ((S) + 1) & 15;                      \
      const size_t tB = ((size_t)(nn * 16 + nk)) * 16384;                      \
      _Pragma("unroll")                                                        \
      for (int n = 0; n < 4; ++n) {                                            \
        BNH[n] = *reinterpret_cast<const bf16x8*>(et_hi + tB + foff[n]);       \
        BNL[n] = *reinterpret_cast<const bf16x8*>(et_lo + tB + foff[n]);       \
      }                                                                        \
      char* dA = smem + ((CUR) ^ 1) * 16384;                                   \
      gld16(ztile_h + (size_t)nk * 8192 + toff, dA + toff);                    \
      gld16(ztile_l + (size_t)nk * 8192 + toff, dA + 8192 + toff);             \
    }                                                                          \
    const char* A = smem + (CUR) * 16384;                                      \
    bf16x8 ah[4], al[4];                                                       \
    _Pragma("unroll")                                                          \
    for (int m = 0; m < 4; ++m) {                                              \
      ah[m] = *reinterpret_cast<const bf16x8*>(A + aoff[m]);                   \
      al[m] = *reinterpret_cast<const bf16x8*>(A + 8192 + aoff[m]);            \
    }                                                                          \
    _Pragma("unroll")                                                          \
    for (int m = 0; m < 4; ++m)                                                \
      _Pragma("unroll")                                                        \
      for (int n = 0; n < 4; ++n)                                              \
        acc[m][n] = __builtin_amdgcn_mfma_f32_16x16x32_bf16(ah[m], BCH[n], acc[m][n], 0, 0, 0); \
    _Pragma("unroll")                                                          \
    for (int m = 0; m < 4; ++m)                                                \
      _Pragma("unroll")                                                        \
      for (int n = 0; n < 4; ++n)                                              \
        acc[m][n] = __builtin_amdgcn_mfma_f32_16x16x32_bf16(ah[m], BCL[n], acc[m][n], 0, 0, 0); \
    _Pragma("unroll")                                                          \
    for (int m = 0; m < 4; ++m)                                                \
      _Pragma("unroll")                                                        \
      for (int n = 0; n < 4; ++n)                                              \
        acc[m][n] = __builtin_amdgcn_mfma_f32_16x16x32_bf16(al[m], BCH[n], acc[m][n], 0, 0, 0); \
    if (((S) & 15) == 15) {                                                    \
      const int nc_ = (S) >> 4;                                                \
      _Pragma("unroll")                                                        \
      for (int n = 0; n < 4; ++n) {                                            \
        const int col = nc_ * 256 + wcol * 64 + n * 16 + lr;                   \
        const float en = enorm[col];                                           \
        _Pragma("unroll")                                                      \
        for (int m = 0; m < 4; ++m) {                                          \
          _Pragma("unroll")                                                    \
          for (int q = 0; q < 4; ++q) {                                        \
            float dv = en - 2.0f * acc[m][n][q];                               \
            int sl = m * 4 + q;                                                \
            if (dv < b1v[sl]) { b2v[sl] = b1v[sl]; b1v[sl] = dv; i1v[sl] = col; } \
            else if (dv < b2v[sl]) b2v[sl] = dv;                               \
          }                                                                    \
        }                                                                      \
      }                                                                        \
      _Pragma("unroll")                                                        \
      for (int m = 0; m < 4; ++m)                                              \
        _Pragma("unroll")                                                      \
        for (int n = 0; n < 4; ++n) acc[m][n] = (f32x4)(0.f);                  \
    }                                                                          \
    __syncthreads();                                                           \
  }

__global__ __launch_bounds__(512) void vq_mfma(const char* __restrict__ zt_hi,
                                               const char* __restrict__ zt_lo,
                                               const char* __restrict__ et_hi,
                                               const char* __restrict__ et_lo,
                                               const float* __restrict__ enorm,
                                               const float* __restrict__ e,
                                               float* __restrict__ out,
                                               int* __restrict__ cnt,
                                               int* __restrict__ list) {
    // A0 16K | A1 16K  (B never touches LDS)
    __shared__ __align__(16) char smem[32768];

    const int t = threadIdx.x;
    const int w = t >> 6, l = t & 63;
    const int lr = l & 15, hg = l >> 4;          // hg = k-granule 0..3
    const int wrow = w >> 2;                      // 0..1  -> rows wrow*64
    const int wcol = w & 3;                       // 0..3  -> cols wcol*64
    const int mb = blockIdx.x;
    const int n0 = mb * 128;

    const int swz = swz_slot(lr, hg) << 4;        // (r>>1)&3 dep only on lr bits
    int aoff[4];
    #pragma unroll
    for (int m = 0; m < 4; ++m) aoff[m] = (wrow * 64 + m * 16 + lr) * 64 + swz;
    size_t foff[4];
    #pragma unroll
    for (int n = 0; n < 4; ++n) foff[n] = (size_t)(wcol * 4 + n) * 1024 + (size_t)l * 16;

    float b1v[16], b2v[16]; int i1v[16];
    #pragma unroll
    for (int s = 0; s < 16; ++s) { b1v[s] = FLT_MAX; b2v[s] = FLT_MAX; i1v[s] = 0; }

    const char* ztile_h = zt_hi + (size_t)mb * 16 * 8192;
    const char* ztile_l = zt_lo + (size_t)mb * 16 * 8192;
    const int toff = t * 16;

    f32x4 acc[4][4];
    #pragma unroll
    for (int m = 0; m < 4; ++m)
        #pragma unroll
        for (int n = 0; n < 4; ++n) acc[m][n] = (f32x4)(0.f);

    bf16x8 b0h[4], b0l[4], b1h[4], b1l[4];

    // prologue: B(0) into b0 regs, A(0) into buf0
    #pragma unroll
    for (int n = 0; n < 4; ++n) {
        b0h[n] = *reinterpret_cast<const bf16x8*>(et_hi + foff[n]);
        b0l[n] = *reinterpret_cast<const bf16x8*>(et_lo + foff[n]);
    }
    gld16(ztile_h + toff, smem + toff);
    gld16(ztile_l + toff, smem + 8192 + toff);
    __syncthreads();

    for (int sp = 0; sp < 32; ++sp) {
        VQ_STEP(sp * 2,     0, b0h, b0l, b1h, b1l);
        VQ_STEP(sp * 2 + 1, 1, b1h, b1l, b0h, b0l);
    }

    // ---- cross-lane butterfly over the 16 col-lanes sharing each row
    #pragma unroll
    for (int s = 0; s < 16; ++s) {
        #pragma unroll
        for (int off = 1; off <= 8; off <<= 1) {
            float ob1 = __shfl_xor(b1v[s], off, 64);
            int   oi1 = __shfl_xor(i1v[s], off, 64);
            float ob2 = __shfl_xor(b2v[s], off, 64);
            if (ob1 < b1v[s] || (ob1 == b1v[s] && oi1 < i1v[s])) {
                b2v[s] = fminf(b1v[s], ob2);
                b1v[s] = ob1; i1v[s] = oi1;
            } else {
                b2v[s] = fminf(b2v[s], ob1);
            }
        }
    }
    // ---- block reduction across the 4 col-waves (overlay on A region)
    float* red_b1 = reinterpret_cast<float*>(smem);          // [128][4]
    float* red_b2 = reinterpret_cast<float*>(smem + 2048);   // [128][4]
    int*   red_i1 = reinterpret_cast<int*>  (smem + 4096);   // [128][4]
    int*   idx_f  = reinterpret_cast<int*>  (smem + 6144);   // [128]
    if (lr == 0) {
        #pragma unroll
        for (int s = 0; s < 16; ++s) {
            int row = wrow * 64 + (s >> 2) * 16 + hg * 4 + (s & 3);
            red_b1[row * 4 + wcol] = b1v[s];
            red_b2[row * 4 + wcol] = b2v[s];
            red_i1[row * 4 + wcol] = i1v[s];
        }
    }
    __syncthreads();
    if (t < 128) {
        float B1 = red_b1[t * 4], B2 = red_b2[t * 4];
        int   I1 = red_i1[t * 4];
        #pragma unroll
        for (int c = 1; c < 4; ++c) {
            float c1 = red_b1[t * 4 + c], c2 = red_b2[t * 4 + c];
            int   ci = red_i1[t * 4 + c];
            if (c1 < B1 || (c1 == B1 && ci < I1)) { B2 = fminf(B1, c2); B1 = c1; I1 = ci; }
            else                                   { B2 = fminf(B2, c1); }
        }
        idx_f[t] = I1;
        out[IOFF + n0 + t] = (float)I1;
        if (B2 - B1 < DELTA) {
            int pos = atomicAdd(cnt, 1);
            list[pos] = n0 + t;
        }
    }
    if (mb == 0 && t == 0) out[SOFF] = 0.0f;
    __syncthreads();

    // ---- gather epilogue: out[b][c][hw0+row] = e[idx[row]][c]
    const int b   = mb >> 3;
    const int hw0 = (mb & 7) * 128;
    const int row4 = (t & 31) * 4;
    const int i0 = idx_f[row4 + 0];
    const int i1g = idx_f[row4 + 1];
    const int i2 = idx_f[row4 + 2];
    const int i3 = idx_f[row4 + 3];
    const int cbase = t >> 5;   // 0..15
    #pragma unroll 4
    for (int p = 0; p < 32; ++p) {
        int c = cbase + (p << 4);
        float4 v;
        v.x = e[(size_t)i0  * DIM + c];
        v.y = e[(size_t)i1g * DIM + c];
        v.z = e[(size_t)i2  * DIM + c];
        v.w = e[(size_t)i3  * DIM + c];
        *reinterpret_cast<float4*>(&out[((size_t)(b * DIM + c)) * HW + hw0 + row4]) = v;
    }
}

// ---------------- Recheck: lane-parallel exact fp32 re-scan ----------------
__global__ __launch_bounds__(256) void recheck(const float* __restrict__ z,
                                               const float* __restrict__ e,
                                               const float* __restrict__ enorm,
                                               const int* __restrict__ cnt,
                                               const int* __restrict__ list,
                                               float* __restrict__ out) {
    __shared__ float zrow[512];
    __shared__ float rbest[256];
    __shared__ int   ribi[256];
    __shared__ int   s_fbi;
    const int t = threadIdx.x;
    const int count = *cnt;
    for (int i = blockIdx.x; i < count; i += gridDim.x) {
        const int row = list[i];
        const int b  = row >> 10;
        const int hw = row & (HW - 1);
        __syncthreads();
        zrow[t]       = z[((size_t)(b * DIM + t))       * HW + hw];
        zrow[t + 256] = z[((size_t)(b * DIM + t + 256)) * HW + hw];
        __syncthreads();
        const float4* zr = reinterpret_cast<const float4*>(zrow);
        float best = FLT_MAX; int bi = 0;
        #pragma unroll
        for (int p = 0; p < 4; ++p) {     // ascending ke => strict < keeps lowest index
            const int ke = t + p * 256;
            const float4* ep = reinterpret_cast<const float4*>(e + (size_t)ke * DIM);
            float s0 = 0.f, s1 = 0.f, s2 = 0.f, s3 = 0.f;
            for (int c = 0; c < 128; c += 4) {
                float4 e0 = ep[c],     z0 = zr[c];
                float4 e1 = ep[c + 1], z1 = zr[c + 1];
                float4 e2 = ep[c + 2], z2 = zr[c + 2];
                float4 e3 = ep[c + 3], z3 = zr[c + 3];
                s0 += e0.x*z0.x + e0.y*z0.y + e0.z*z0.z + e0.w*z0.w;
                s1 += e1.x*z1.x + e1.y*z1.y + e1.z*z1.z + e1.w*z1.w;
                s2 += e2.x*z2.x + e2.y*z2.y + e2.z*z2.z + e2.w*z2.w;
                s3 += e3.x*z3.x + e3.y*z3.y + e3.z*z3.z + e3.w*z3.w;
            }
            float dist = enorm[ke] - 2.0f * (((s0 + s1) + (s2 + s3)));
            if (dist < best) { best = dist; bi = ke; }
        }
        rbest[t] = best; ribi[t] = bi;
        __syncthreads();
        #pragma unroll
        for (int s = 128; s > 0; s >>= 1) {
            if (t < s) {
                float ov = rbest[t + s]; int oi = ribi[t + s];
                if (ov < rbest[t] || (ov == rbest[t] && oi < ribi[t])) {
                    rbest[t] = ov; ribi[t] = oi;
                }
            }
            __syncthreads();
        }
        if (t == 0) {
            s_fbi = ribi[0];
            out[IOFF + row] = (float)ribi[0];
        }
        __syncthreads();
        const int fbi = s_fbi;
        out[((size_t)(b * DIM + t))       * HW + hw] = e[(size_t)fbi * DIM + t];
        out[((size_t)(b * DIM + t + 256)) * HW + hw] = e[(size_t)fbi * DIM + t + 256];
    }
}

// ======================= fp32 fallback path (round-2, proven) ================
constexpr int TM = 64;
constexpr int TN = 256;
constexpr int KC = 32;
constexpr int ZST = 68;
constexpr int EST = 260;

union F4 { float4 v; float f[4]; };

__global__ __launch_bounds__(256) void enorm_kernel(const float* __restrict__ e,
                                                    float* __restrict__ enorm) {
    int gid  = blockIdx.x * 256 + threadIdx.x;
    int wave = gid >> 6;
    int lane = gid & 63;
    if (wave >= NEMB) return;
    const float* row = e + (size_t)wave * DIM;
    float4 a = *reinterpret_cast<const float4*>(row + lane * 8);
    float4 b = *reinterpret_cast<const float4*>(row + lane * 8 + 4);
    float s = a.x*a.x + a.y*a.y + a.z*a.z + a.w*a.w
            + b.x*b.x + b.y*b.y + b.z*b.z + b.w*b.w;
    #pragma unroll
    for (int off = 32; off > 0; off >>= 1) s += __shfl_down(s, off, 64);
    if (lane == 0) enorm[wave] = s;
}

__global__ __launch_bounds__(256) void vq_main_kernel(const float* __restrict__ z,
                                                      const float* __restrict__ e,
                                                      const float* __restrict__ enorm,
                                                      float* __restrict__ out) {
    __shared__ float zs[KC][ZST];
    __shared__ float es[KC][EST];
    __shared__ float enorm_l[NEMB];
    __shared__ int   idx_f[TM];

    const int t   = threadIdx.x;
    const int n0  = blockIdx.x * TM;
    const int b   = n0 >> 10;
    const int hw0 = n0 & (HW - 1);
    const float* zb = z + ((size_t)b * DIM) * HW + hw0;

    #pragma unroll
    for (int i = 0; i < 4; ++i) enorm_l[t + i * 256] = enorm[t + i * 256];

    const int rg = t >> 5;
    const int cg = t & 31;

    float best[8];
    int   bidx[8];
    #pragma unroll
    for (int i = 0; i < 8; ++i) { best[i] = FLT_MAX; bidx[i] = 0; }

    const int z_r4 = (t & 15) * 4;
    const int z_c  = t >> 4;
    const int e_ke = t >> 3;
    const int e_c4 = t & 7;

    for (int nc = 0; nc < NEMB / TN; ++nc) {
        const int k0 = nc * TN;
        float acc[8][8];
        #pragma unroll
        for (int mi = 0; mi < 8; ++mi)
            #pragma unroll
            for (int nj = 0; nj < 8; ++nj) acc[mi][nj] = 0.f;

        for (int kc = 0; kc < DIM / KC; ++kc) {
            const int c0 = kc * KC;
            __syncthreads();
            #pragma unroll
            for (int p = 0; p < 2; ++p) {
                int c = z_c + p * 16;
                float4 v = *reinterpret_cast<const float4*>(zb + (size_t)(c0 + c) * HW + z_r4);
                *reinterpret_cast<float4*>(&zs[c][z_r4]) = v;
            }
            #pragma unroll
            for (int p = 0; p < 8; ++p) {
                int ke = e_ke + p * 32;
                float4 v = *reinterpret_cast<const float4*>(e + (size_t)(k0 + ke) * DIM + c0 + e_c4 * 4);
                es[e_c4 * 4 + 0][ke] = v.x;
                es[e_c4 * 4 + 1][ke] = v.y;
                es[e_c4 * 4 + 2][ke] = v.z;
                es[e_c4 * 4 + 3][ke] = v.w;
            }
            __syncthreads();
            #pragma unroll
            for (int kk = 0; kk < KC; ++kk) {
                F4 zf0, zf1, ef0, ef1;
                zf0.v = *reinterpret_cast<const float4*>(&zs[kk][rg * 8]);
                zf1.v = *reinterpret_cast<const float4*>(&zs[kk][rg * 8 + 4]);
                ef0.v = *reinterpret_cast<const float4*>(&es[kk][cg * 4]);
                ef1.v = *reinterpret_cast<const float4*>(&es[kk][128 + cg * 4]);
                #pragma unroll
                for (int mi = 0; mi < 4; ++mi) {
                    #pragma unroll
                    for (int nj = 0; nj < 4; ++nj) {
                        acc[mi][nj]         += zf0.f[mi] * ef0.f[nj];
                        acc[mi][nj + 4]     += zf0.f[mi] * ef1.f[nj];
                        acc[mi + 4][nj]     += zf1.f[mi] * ef0.f[nj];
                        acc[mi + 4][nj + 4] += zf1.f[mi] * ef1.f[nj];
                    }
                }
            }
        }
        #pragma unroll
        for (int mi = 0; mi < 8; ++mi) {
            #pragma unroll
            for (int nj = 0; nj < 8; ++nj) {
                int col = k0 + (nj < 4 ? cg * 4 + nj : 128 + cg * 4 + (nj - 4));
                float dv = enorm_l[col] - 2.0f * acc[mi][nj];
                if (dv < best[mi]) { best[mi] = dv; bidx[mi] = col; }
            }
        }
    }

    __syncthreads();
    float* best_l = reinterpret_cast<float*>(es);
    int*   idx_l  = reinterpret_cast<int*>(reinterpret_cast<char*>(es) + (size_t)TM * 33 * 4);
    #pragma unroll
    for (int mi = 0; mi < 8; ++mi) {
        int row = rg * 8 + mi;
        best_l[row * 33 + cg] = best[mi];
        idx_l[row * 33 + cg]  = bidx[mi];
    }
    __syncthreads();
    if (t < TM) {
        float bv = best_l[t * 33];
        int   bi = idx_l[t * 33];
        #pragma unroll
        for (int c = 1; c < 32; ++c) {
            float v  = best_l[t * 33 + c];
            int   ix = idx_l[t * 33 + c];
            if (v < bv || (v == bv && ix < bi)) { bv = v; bi = ix; }
        }
        idx_f[t] = bi;
        out[IOFF + n0 + t] = (float)bi;
    }
    if (blockIdx.x == 0 && t == 0) out[SOFF] = 0.0f;
    __syncthreads();

    const int row4 = (t & 15) * 4;
    const int i0 = idx_f[row4 + 0];
    const int i1 = idx_f[row4 + 1];
    const int i2 = idx_f[row4 + 2];
    const int i3 = idx_f[row4 + 3];
    #pragma unroll 4
    for (int p = 0; p < 32; ++p) {
        int c = (t >> 4) + (p << 4);
        float4 v;
        v.x = e[(size_t)i0 * DIM + c];
        v.y = e[(size_t)i1 * DIM + c];
        v.z = e[(size_t)i2 * DIM + c];
        v.w = e[(size_t)i3 * DIM + c];
        *reinterpret_cast<float4*>(&out[((size_t)(b * DIM + c)) * HW + hw0 + row4]) = v;
    }
}

// ---------------- host launcher ----------------
extern "C" void kernel_launch(void* const* d_in, const int* in_sizes, int n_in,
                              void* d_out, int out_size, void* d_ws, size_t ws_size,
                              hipStream_t stream) {
    const float* z = (const float*)d_in[0];
    const float* e = (const float*)d_in[1];
    float* out = (float*)d_out;
    char*  ws  = (char*)d_ws;

    if (ws_size >= WS_NEED) {
        char*  zt_hi = ws + WS_ZHI;
        char*  zt_lo = ws + WS_ZLO;
        char*  et_hi = ws + WS_EHI;
        char*  et_lo = ws + WS_ELO;
        float* enorm = (float*)(ws + WS_ENORM);
        int*   cnt   = (int*)(ws + WS_CNT);
        int*   list  = (int*)(ws + WS_LIST);

        hipLaunchKernelGGL(enorm_prep, dim3(NEMB / 4), dim3(256), 0, stream, e, enorm, cnt);
        hipLaunchKernelGGL(eprep,      dim3(256),      dim3(256), 0, stream, e, et_hi, et_lo);
        hipLaunchKernelGGL(zprep,      dim3(2048),     dim3(256), 0, stream, z, zt_hi, zt_lo);
        hipLaunchKernelGGL(vq_mfma,    dim3(NROW / 128), dim3(512), 0, stream,
                           zt_hi, zt_lo, et_hi, et_lo, enorm, e, out, cnt, list);
        hipLaunchKernelGGL(recheck,    dim3(256),      dim3(256), 0, stream,
                           z, e, enorm, cnt, list, out);
    } else {
        float* enorm = (float*)ws;
        hipLaunchKernelGGL(enorm_kernel,   dim3(NEMB / 4), dim3(256), 0, stream, e, enorm);
        hipLaunchKernelGGL(vq_main_kernel, dim3(NROW / TM), dim3(256), 0, stream,
                           z, e, enorm, out);
    }
}